// Round 2
// baseline (742.937 us; speedup 1.0000x reference)
//
#include <hip/hip_runtime.h>
#include <hip/hip_bf16.h>

typedef short v8s __attribute__((ext_vector_type(8)));   // 8 x bf16 (4 VGPRs)
typedef float v4f __attribute__((ext_vector_type(4)));   // MFMA accumulator

#define NT   1024
#define NVX  65536
#define KTRUE 257
#define KP   272      // 257 padded to 17*16
#define NXO  2048

// ---------- helpers ----------
static __device__ __forceinline__ unsigned short f2bf(float f) {
  unsigned int u = __float_as_uint(f);
  u += 0x7FFFu + ((u >> 16) & 1u);          // RNE
  return (unsigned short)(u >> 16);
}
static __device__ __forceinline__ unsigned int pk2bf(float a, float b) {
  return (unsigned int)f2bf(a) | ((unsigned int)f2bf(b) << 16);
}

// ---------- k0: pad W3 -> w3p[32][272], b3 -> b3p[272] ----------
__global__ void k0_prep(const float* __restrict__ W3, const float* __restrict__ b3,
                        float* __restrict__ w3p, float* __restrict__ b3p) {
  int k = threadIdx.x;
  if (k >= KP) return;
  int j = blockIdx.x;
  if (j < 32) w3p[j*KP + k] = (k < KTRUE) ? W3[j*KTRUE + k] : 0.f;
  else        b3p[k]        = (k < KTRUE) ? b3[k] : 0.f;
}

// ---------- k1a: per-point MLP layers 1+2 -> H2[65536][32] f32 (relu applied) ----------
__global__ __launch_bounds__(128) void k1a_h2(
    const float* __restrict__ xs, const float* __restrict__ vs,
    const float* __restrict__ W1, const float* __restrict__ b1,
    const float* __restrict__ W2, const float* __restrict__ b2,
    float* __restrict__ H2) {
  int vx = blockIdx.x * 128 + threadIdx.x;
  float x = xs[vx & 511];
  float v = vs[vx >> 9];
  float h2[32];
#pragma unroll
  for (int q = 0; q < 8; ++q) {
    float4 t = ((const float4*)b2)[q];
    h2[q*4+0] = t.x; h2[q*4+1] = t.y; h2[q*4+2] = t.z; h2[q*4+3] = t.w;
  }
#pragma unroll 4
  for (int i = 0; i < 64; ++i) {
    float h1 = fmaf(x, W1[i], fmaf(v, W1[64+i], b1[i]));
    h1 = fmaxf(h1, 0.f);
    const float4* w2r = (const float4*)(W2 + i*32);
#pragma unroll
    for (int q = 0; q < 8; ++q) {
      float4 t = w2r[q];
      h2[q*4+0] = fmaf(h1, t.x, h2[q*4+0]);
      h2[q*4+1] = fmaf(h1, t.y, h2[q*4+1]);
      h2[q*4+2] = fmaf(h1, t.z, h2[q*4+2]);
      h2[q*4+3] = fmaf(h1, t.w, h2[q*4+3]);
    }
  }
  float4* dst = (float4*)(H2 + (size_t)vx * 32);
#pragma unroll
  for (int q = 0; q < 8; ++q) {
    float4 t;
    t.x = fmaxf(h2[q*4+0], 0.f);
    t.y = fmaxf(h2[q*4+1], 0.f);
    t.z = fmaxf(h2[q*4+2], 0.f);
    t.w = fmaxf(h2[q*4+3], 0.f);
    dst[q] = t;
  }
}

// ---------- k1b: PsiT[k][vx] = (b3[k] + sum_j H2[vx][j]*W3[j][k]) * hx*hv  (bf16) ----------
// 2 points per thread; k split in 4 chunks of 68 across blocks.
__global__ __launch_bounds__(256) void k1b_psit(
    const float* __restrict__ H2, const float* __restrict__ w3p,
    const float* __restrict__ b3p, const float* __restrict__ xs,
    const float* __restrict__ vs, unsigned short* __restrict__ PsiT) {
  int kch = blockIdx.x >> 7;        // 0..3
  int vb  = blockIdx.x & 127;
  int p0  = (vb * 256 + threadIdx.x) * 2;
  float scale = (xs[1] - xs[0]) * (vs[1] - vs[0]);   // hx*hv
  float ha[32], hb[32];
  const float4* s = (const float4*)(H2 + (size_t)p0 * 32);
#pragma unroll
  for (int q = 0; q < 8; ++q) {
    float4 t = s[q];
    ha[q*4+0]=t.x; ha[q*4+1]=t.y; ha[q*4+2]=t.z; ha[q*4+3]=t.w;
  }
#pragma unroll
  for (int q = 0; q < 8; ++q) {
    float4 t = s[8+q];
    hb[q*4+0]=t.x; hb[q*4+1]=t.y; hb[q*4+2]=t.z; hb[q*4+3]=t.w;
  }
  int kbeg = kch * 68;
  for (int k4 = kbeg; k4 < kbeg + 68; k4 += 4) {
    float4 bv = *(const float4*)(b3p + k4);
    float a0=bv.x, a1=bv.y, a2=bv.z, a3=bv.w;
    float c0=bv.x, c1=bv.y, c2=bv.z, c3=bv.w;
#pragma unroll
    for (int j = 0; j < 32; ++j) {
      float4 w = *(const float4*)(w3p + j*KP + k4);   // wave-uniform, L1-resident
      a0 = fmaf(ha[j], w.x, a0); a1 = fmaf(ha[j], w.y, a1);
      a2 = fmaf(ha[j], w.z, a2); a3 = fmaf(ha[j], w.w, a3);
      c0 = fmaf(hb[j], w.x, c0); c1 = fmaf(hb[j], w.y, c1);
      c2 = fmaf(hb[j], w.z, c2); c3 = fmaf(hb[j], w.w, c3);
    }
    *(unsigned int*)(PsiT + (size_t)(k4+0)*NVX + p0) = pk2bf(a0*scale, c0*scale);
    *(unsigned int*)(PsiT + (size_t)(k4+1)*NVX + p0) = pk2bf(a1*scale, c1*scale);
    *(unsigned int*)(PsiT + (size_t)(k4+2)*NVX + p0) = pk2bf(a2*scale, c2*scale);
    *(unsigned int*)(PsiT + (size_t)(k4+3)*NVX + p0) = pk2bf(a3*scale, c3*scale);
  }
}

// ---------- k2: split-K bf16 MFMA GEMM: Wpart[kc][t][k] = sum_{vx in chunk} f[t][vx]*PsiT[k][vx]
// grid 512 = 32 k-chunks * 16 M-tiles (64 rows). 4 waves as 2(M)x2(N).
__global__ __launch_bounds__(256, 2) void k2_gemm(
    const float* __restrict__ f, const unsigned short* __restrict__ PsiT,
    float* __restrict__ Wpart) {
  __shared__ __align__(16) unsigned short Al[64*40];   // 64 rows, pad 40 (80B)
  __shared__ __align__(16) unsigned short Bl[KP*40];   // 272 rows, pad 40
  const int tid = threadIdx.x;
  const int kc = blockIdx.x >> 4;
  const int mt = blockIdx.x & 15;
  const int t0 = mt * 64;
  const size_t kbase = (size_t)kc * 2048;
  const int lane = tid & 63;
  const int wave = tid >> 6;
  const int wm = wave >> 1, wn = wave & 1;
  const int frow = lane & 15;
  const int kg = (lane >> 4) * 8;

  v4f acc0[9], acc1[9];
#pragma unroll
  for (int n = 0; n < 9; ++n) {
    acc0[n] = (v4f){0.f,0.f,0.f,0.f};
    acc1[n] = (v4f){0.f,0.f,0.f,0.f};
  }

  const int ar = tid >> 2, ag = tid & 3;
  const float* fbase = f + (size_t)(t0 + ar) * NVX + kbase + ag*8;

  // prefetch step 0 into registers
  float4 pa0 = *(const float4*)(fbase);
  float4 pa1 = *(const float4*)(fbase + 4);
  int4 bpre[5];
#pragma unroll
  for (int it = 0; it < 5; ++it) {
    int c = tid + it*256;
    if (c < 1088) {
      int k = c >> 2, g = c & 3;
      bpre[it] = *(const int4*)(PsiT + (size_t)k*NVX + kbase + g*8);
    }
  }

  for (int step = 0; step < 64; ++step) {
    // write current tile to LDS
    int4 ap;
    ap.x = (int)pk2bf(pa0.x, pa0.y); ap.y = (int)pk2bf(pa0.z, pa0.w);
    ap.z = (int)pk2bf(pa1.x, pa1.y); ap.w = (int)pk2bf(pa1.z, pa1.w);
    *(int4*)&Al[ar*40 + ag*8] = ap;
#pragma unroll
    for (int it = 0; it < 5; ++it) {
      int c = tid + it*256;
      if (c < 1088) *(int4*)&Bl[(c>>2)*40 + (c&3)*8] = bpre[it];
    }
    // prefetch next tile (HBM latency hides under MFMA)
    if (step < 63) {
      const float* fn = fbase + (size_t)(step+1)*32;
      pa0 = *(const float4*)fn; pa1 = *(const float4*)(fn + 4);
#pragma unroll
      for (int it = 0; it < 5; ++it) {
        int c = tid + it*256;
        if (c < 1088) {
          int k = c >> 2, g = c & 3;
          bpre[it] = *(const int4*)(PsiT + (size_t)k*NVX + kbase + (step+1)*32 + g*8);
        }
      }
    }
    __syncthreads();
    v8s a0 = *(const v8s*)&Al[(wm*32 + frow)*40 + kg];
    v8s a1 = *(const v8s*)&Al[(wm*32 + 16 + frow)*40 + kg];
#pragma unroll
    for (int n = 0; n < 9; ++n) {
      v8s b = *(const v8s*)&Bl[((wn*8 + n)*16 + frow)*40 + kg];
      acc0[n] = __builtin_amdgcn_mfma_f32_16x16x32_bf16(a0, b, acc0[n], 0, 0, 0);
      acc1[n] = __builtin_amdgcn_mfma_f32_16x16x32_bf16(a1, b, acc1[n], 0, 0, 0);
    }
    __syncthreads();
  }
  // epilogue: C/D layout col=lane&15, row=(lane>>4)*4+reg  [m89-verified]
  float* dst = Wpart + (size_t)kc * (NT*KP);
  const int r4 = (lane >> 4) * 4;
#pragma unroll
  for (int n = 0; n < 9; ++n) {
    if (wn && n == 0) continue;         // tile 8 computed by both, stored by wn==0 only
    int col = (wn*8 + n)*16 + frow;
#pragma unroll
    for (int r = 0; r < 4; ++r) {
      dst[(size_t)(t0 + wm*32 + r4 + r)*KP + col]      = acc0[n][r];
      dst[(size_t)(t0 + wm*32 + 16 + r4 + r)*KP + col] = acc1[n][r];
    }
  }
}

// ---------- k2b: Wsum = sum_kc Wpart ----------
__global__ __launch_bounds__(256) void k2b_reduce(const float* __restrict__ Wpart,
                                                  float* __restrict__ Wsum) {
  int idx = blockIdx.x * 256 + threadIdx.x;       // < 1024*272
  float s = 0.f;
#pragma unroll 8
  for (int kc = 0; kc < 32; ++kc) s += Wpart[(size_t)kc * (NT*KP) + idx];
  Wsum[idx] = s;
}

// ---------- k2c: phi[272][2048] (rows >=257 zero) ----------
__global__ __launch_bounds__(256) void k2c_phi(const float* __restrict__ x_out,
                                               const float* __restrict__ xs,
                                               float* __restrict__ phi) {
  int idx = blockIdx.x * 256 + threadIdx.x;       // < 272*2048
  int k = idx >> 11, xo = idx & 2047;
  float wmul = 6.283185307179586f / (xs[511] - xs[0]);
  float x = x_out[xo];
  float val;
  if (k < 128)        val = sinf((float)(k+1) * wmul * x);
  else if (k < KTRUE) val = cosf((float)(k-128) * wmul * x);
  else                val = 0.f;
  phi[idx] = val;
}

// ---------- k3: out[1024][2048] = Wsum[1024][272] @ phi[272][2048]  (fp32 tiled) ----------
__global__ __launch_bounds__(256) void k3_out(
    const float* __restrict__ Wsum, const float* __restrict__ phi,
    float* __restrict__ out) {
  __shared__ float At[16*64];      // A transposed: [kk][row]
  __shared__ float Bp[16*132];     // [tc][kk][8] padded to 132 per tc
  const int tid = threadIdx.x;
  const int bt = blockIdx.x >> 4;   // 16 t-blocks of 64
  const int bx = blockIdx.x & 15;   // 16 xo-blocks of 128
  const int t0 = bt*64, xo0 = bx*128;
  const int tr = tid >> 4, tc = tid & 15;   // thread tile 4 rows x 8 cols
  float acc[4][8];
#pragma unroll
  for (int r = 0; r < 4; ++r)
#pragma unroll
    for (int c = 0; c < 8; ++c) acc[r][c] = 0.f;

  for (int ks = 0; ks < 17; ++ks) {
    int k0 = ks * 16;
    {
      int r = tid >> 2, cq = (tid & 3) * 4;
      float4 t = *(const float4*)(Wsum + (size_t)(t0 + r)*KP + k0 + cq);
      At[(cq+0)*64 + r] = t.x;
      At[(cq+1)*64 + r] = t.y;
      At[(cq+2)*64 + r] = t.z;
      At[(cq+3)*64 + r] = t.w;
    }
#pragma unroll
    for (int it = 0; it < 2; ++it) {
      int q = tid + it*256;
      int kk = q >> 5, c4 = (q & 31) * 4;
      float4 t = *(const float4*)(phi + (size_t)(k0 + kk)*NXO + xo0 + c4);
      int tcb = c4 >> 3, sub = c4 & 7;
      *(float4*)&Bp[tcb*132 + kk*8 + sub] = t;
    }
    __syncthreads();
#pragma unroll
    for (int kk = 0; kk < 16; ++kk) {
      float4 av = *(const float4*)&At[kk*64 + tr*4];
      float4 b0 = *(const float4*)&Bp[tc*132 + kk*8];
      float4 b1 = *(const float4*)&Bp[tc*132 + kk*8 + 4];
      float a[4] = {av.x, av.y, av.z, av.w};
      float b[8] = {b0.x, b0.y, b0.z, b0.w, b1.x, b1.y, b1.z, b1.w};
#pragma unroll
      for (int r = 0; r < 4; ++r)
#pragma unroll
        for (int c = 0; c < 8; ++c) acc[r][c] = fmaf(a[r], b[c], acc[r][c]);
    }
    __syncthreads();
  }
#pragma unroll
  for (int r = 0; r < 4; ++r) {
    float4 o0 = {acc[r][0], acc[r][1], acc[r][2], acc[r][3]};
    float4 o1 = {acc[r][4], acc[r][5], acc[r][6], acc[r][7]};
    float* orow = out + (size_t)(t0 + tr*4 + r)*NXO + xo0 + tc*8;
    *(float4*)(orow)     = o0;
    *(float4*)(orow + 4) = o1;
  }
}

// ---------- launch ----------
extern "C" void kernel_launch(void* const* d_in, const int* in_sizes, int n_in,
                              void* d_out, int out_size, void* d_ws, size_t ws_size,
                              hipStream_t stream) {
  (void)in_sizes; (void)n_in; (void)out_size; (void)ws_size;
  const float* x_out = (const float*)d_in[0];
  const float* f     = (const float*)d_in[1];
  const float* xs    = (const float*)d_in[2];
  const float* vs    = (const float*)d_in[3];
  const float* W1    = (const float*)d_in[4];
  const float* b1    = (const float*)d_in[5];
  const float* W2    = (const float*)d_in[6];
  const float* b2    = (const float*)d_in[7];
  const float* W3    = (const float*)d_in[8];
  const float* b3    = (const float*)d_in[9];
  float* out = (float*)d_out;
  char* ws = (char*)d_ws;

  // Workspace map (peak 74.7 MB):
  //   PsiT  [0,            35,651,584)  272*65536*2 bf16
  //   Wpart [35,651,584,   71,303,168)  32*1024*272*4 f32   (written by k2)
  //   H2    [35,651,584,   44,040,192)  65536*32*4 f32      (ALIASES Wpart head:
  //                                      dead after k1b, before k2 writes)
  //   Wsum  [71,303,168,   72,417,280)  1024*272*4
  //   w3p   [72,417,280,   72,452,096)  32*272*4
  //   b3p   [72,452,096,   72,453,184)  272*4
  //   phi   [72,453,184,   74,681,408)  272*2048*4
  unsigned short* PsiT = (unsigned short*)(ws);
  float* Wpart = (float*)(ws + 35651584);
  float* H2ws  = (float*)(ws + 35651584);   // alias (see ordering note above)
  float* Wsum  = (float*)(ws + 71303168);
  float* w3p   = (float*)(ws + 72417280);
  float* b3p   = (float*)(ws + 72452096);
  float* phi   = (float*)(ws + 72453184);

  hipLaunchKernelGGL(k0_prep,   dim3(33),   dim3(320), 0, stream, W3, b3, w3p, b3p);
  hipLaunchKernelGGL(k1a_h2,    dim3(512),  dim3(128), 0, stream, xs, vs, W1, b1, W2, b2, H2ws);
  hipLaunchKernelGGL(k1b_psit,  dim3(512),  dim3(256), 0, stream, H2ws, w3p, b3p, xs, vs, PsiT);
  hipLaunchKernelGGL(k2c_phi,   dim3(2176), dim3(256), 0, stream, x_out, xs, phi);
  hipLaunchKernelGGL(k2_gemm,   dim3(512),  dim3(256), 0, stream, f, PsiT, Wpart);
  hipLaunchKernelGGL(k2b_reduce,dim3(1088), dim3(256), 0, stream, Wpart, Wsum);
  hipLaunchKernelGGL(k3_out,    dim3(256),  dim3(256), 0, stream, Wsum, phi, out);
}

// Round 3
// 467.614 us; speedup vs baseline: 1.5888x; 1.5888x over previous
//
#include <hip/hip_runtime.h>
#include <hip/hip_bf16.h>

typedef short v8s __attribute__((ext_vector_type(8)));   // 8 x bf16 (4 VGPRs)
typedef float v4f __attribute__((ext_vector_type(4)));   // MFMA accumulator

#define NT   1024
#define NVX  65536
#define KTRUE 257
#define KP   272      // 257 padded to 17*16
#define NXO  2048
#define NJ   48       // 32 H2 cols + 1 ones col + 15 pad (3 n-tiles of 16)
#define NKC  64       // split-K chunks in k2 (K-chunk = 1024)

// ---------- helpers ----------
static __device__ __forceinline__ unsigned short f2bf(float f) {
  unsigned int u = __float_as_uint(f);
  u += 0x7FFFu + ((u >> 16) & 1u);          // RNE
  return (unsigned short)(u >> 16);
}

// ---------- k0: W3e[48][272]: rows 0..31 = W3, row 32 = b3, rows 33..47 = 0; cols>=257 = 0
__global__ void k0_prep(const float* __restrict__ W3, const float* __restrict__ b3,
                        float* __restrict__ W3e) {
  int k = threadIdx.x;
  if (k >= KP) return;
  int j = blockIdx.x;        // 0..47
  float val = 0.f;
  if (k < KTRUE) {
    if (j < 32)       val = W3[j*KTRUE + k];
    else if (j == 32) val = b3[k];
  }
  W3e[j*KP + k] = val;
}

// ---------- k1: full MLP per (x,v) point -> H2T[j][vx] bf16 (j=0..31), row 32 = ones
__global__ __launch_bounds__(256) void k1_mlp(
    const float* __restrict__ xs, const float* __restrict__ vs,
    const float* __restrict__ W1, const float* __restrict__ b1,
    const float* __restrict__ W2, const float* __restrict__ b2,
    unsigned short* __restrict__ H2T) {
  int vx = blockIdx.x * 256 + threadIdx.x;
  float x = xs[vx & 511];
  float v = vs[vx >> 9];
  float h2[32];
#pragma unroll
  for (int q = 0; q < 8; ++q) {
    float4 t = ((const float4*)b2)[q];
    h2[q*4+0] = t.x; h2[q*4+1] = t.y; h2[q*4+2] = t.z; h2[q*4+3] = t.w;
  }
#pragma unroll 4
  for (int i = 0; i < 64; ++i) {
    float h1 = fmaf(x, W1[i], fmaf(v, W1[64+i], b1[i]));
    h1 = fmaxf(h1, 0.f);
    const float4* w2r = (const float4*)(W2 + i*32);
#pragma unroll
    for (int q = 0; q < 8; ++q) {
      float4 t = w2r[q];
      h2[q*4+0] = fmaf(h1, t.x, h2[q*4+0]);
      h2[q*4+1] = fmaf(h1, t.y, h2[q*4+1]);
      h2[q*4+2] = fmaf(h1, t.z, h2[q*4+2]);
      h2[q*4+3] = fmaf(h1, t.w, h2[q*4+3]);
    }
  }
#pragma unroll
  for (int j = 0; j < 32; ++j)
    H2T[(size_t)j*NVX + vx] = f2bf(fmaxf(h2[j], 0.f));
  H2T[(size_t)32*NVX + vx] = 0x3F80;   // 1.0 bf16  (rows 33..47 left garbage:
                                       //  multiplied by W3e rows 33..47 == 0)
}

// ---------- k2: streaming split-K bf16 MFMA GEMM (no LDS, no barriers)
// Gpart[kc][t][j] = sum_{vx in chunk kc} f[t][vx] * H2T[j][vx]
// grid = 64 kc * 16 mt; block 256 = 4 waves, wave w owns rows mt*64 + w*16 .. +16, all 48 j.
__global__ __launch_bounds__(256) void k2_gemm(
    const float* __restrict__ f, const unsigned short* __restrict__ H2T,
    float* __restrict__ Gpart) {
  const int tid  = threadIdx.x;
  const int kc   = blockIdx.x >> 4;     // 0..63
  const int mt   = blockIdx.x & 15;     // 0..15
  const int wave = tid >> 6;
  const int lane = tid & 63;
  const int frow = lane & 15;
  const int kg   = (lane >> 4) * 8;     // k offset (elements) within 32-wide step
  const int row  = mt*64 + wave*16 + frow;
  const size_t kbase = (size_t)kc * 1024;

  const float* fp = f + (size_t)row * NVX + kbase + kg;
  const unsigned short* bp0 = H2T + (size_t)(frow)      * NVX + kbase + kg;
  const unsigned short* bp1 = H2T + (size_t)(16 + frow) * NVX + kbase + kg;
  const unsigned short* bp2 = H2T + (size_t)(32 + frow) * NVX + kbase + kg;

  v4f acc0 = {0.f,0.f,0.f,0.f}, acc1 = {0.f,0.f,0.f,0.f}, acc2 = {0.f,0.f,0.f,0.f};

#pragma unroll 4
  for (int step = 0; step < 32; ++step) {
    const int o = step * 32;
    float4 fa = *(const float4*)(fp + o);
    float4 fb = *(const float4*)(fp + o + 4);
    union { v8s v; __hip_bfloat162 h[4]; } au;
    au.h[0] = __float22bfloat162_rn(float2{fa.x, fa.y});
    au.h[1] = __float22bfloat162_rn(float2{fa.z, fa.w});
    au.h[2] = __float22bfloat162_rn(float2{fb.x, fb.y});
    au.h[3] = __float22bfloat162_rn(float2{fb.z, fb.w});
    v8s b0 = *(const v8s*)(bp0 + o);
    v8s b1 = *(const v8s*)(bp1 + o);
    v8s b2 = *(const v8s*)(bp2 + o);
    acc0 = __builtin_amdgcn_mfma_f32_16x16x32_bf16(au.v, b0, acc0, 0, 0, 0);
    acc1 = __builtin_amdgcn_mfma_f32_16x16x32_bf16(au.v, b1, acc1, 0, 0, 0);
    acc2 = __builtin_amdgcn_mfma_f32_16x16x32_bf16(au.v, b2, acc2, 0, 0, 0);
  }

  // C/D layout: col = lane&15, row = (lane>>4)*4 + reg   [m89-verified, round-2-passing]
  float* g = Gpart + (size_t)kc * (NT*NJ) + (size_t)(mt*64 + wave*16) * NJ;
  const int r4 = (lane >> 4) * 4;
#pragma unroll
  for (int r = 0; r < 4; ++r) {
    g[(r4 + r)*NJ +      frow] = acc0[r];
    g[(r4 + r)*NJ + 16 + frow] = acc1[r];
    g[(r4 + r)*NJ + 32 + frow] = acc2[r];
  }
}

// ---------- k2b: Gsum = sum_kc Gpart; Wsum[t][k] = scale * sum_{j<33} Gsum[t][j]*W3e[j][k]
// grid 256 blocks * 256 thr; wave w handles row t = blk*4 + w.
__global__ __launch_bounds__(256) void k2b_wsum(
    const float* __restrict__ Gpart, const float* __restrict__ W3e,
    const float* __restrict__ xs, const float* __restrict__ vs,
    float* __restrict__ Wsum) {
  __shared__ float gs[4][48];
  const int tid = threadIdx.x, wave = tid >> 6, lane = tid & 63;
  const int t = blockIdx.x * 4 + wave;
  const float scale = (xs[1] - xs[0]) * (vs[1] - vs[0]);   // hx*hv
  if (lane < 48) {
    float s = 0.f;
    const float* gp = Gpart + (size_t)t * NJ + lane;
#pragma unroll 8
    for (int kc = 0; kc < NKC; ++kc) s += gp[(size_t)kc * (NT*NJ)];
    gs[wave][lane] = s;
  }
  __syncthreads();
#pragma unroll
  for (int i = 0; i < 5; ++i) {
    int k = lane + i*64;
    if (k < KP) {
      float acc = 0.f;
#pragma unroll
      for (int j = 0; j < 33; ++j) acc = fmaf(gs[wave][j], W3e[j*KP + k], acc);
      Wsum[(size_t)t*KP + k] = acc * scale;
    }
  }
}

// ---------- k2c: phi[272][2048] (rows >=257 zero) ----------
__global__ __launch_bounds__(256) void k2c_phi(const float* __restrict__ x_out,
                                               const float* __restrict__ xs,
                                               float* __restrict__ phi) {
  int idx = blockIdx.x * 256 + threadIdx.x;       // < 272*2048
  int k = idx >> 11, xo = idx & 2047;
  float wmul = 6.283185307179586f / (xs[511] - xs[0]);
  float x = x_out[xo];
  float val;
  if (k < 128)        val = sinf((float)(k+1) * wmul * x);
  else if (k < KTRUE) val = cosf((float)(k-128) * wmul * x);
  else                val = 0.f;
  phi[idx] = val;
}

// ---------- k3: out[1024][2048] = Wsum[1024][272] @ phi[272][2048]  (fp32 tiled)
// grid 512 = 32 bt(32 rows) * 16 bx(128 cols); thread tile 2x8.
__global__ __launch_bounds__(256) void k3_out(
    const float* __restrict__ Wsum, const float* __restrict__ phi,
    float* __restrict__ out) {
  __shared__ float At[16][32];     // [kk][row]
  __shared__ float Bp[16*132];     // [tc][kk*8+sub], 132-pad per tc
  const int tid = threadIdx.x;
  const int bt = blockIdx.x >> 4;   // 0..31
  const int bx = blockIdx.x & 15;   // 0..15
  const int t0 = bt*32, xo0 = bx*128;
  const int tr = tid >> 4, tc = tid & 15;   // rows tr*2..+2, cols tc*8..+8
  float acc[2][8];
#pragma unroll
  for (int r = 0; r < 2; ++r)
#pragma unroll
    for (int c = 0; c < 8; ++c) acc[r][c] = 0.f;

  for (int ks = 0; ks < 17; ++ks) {
    int k0 = ks * 16;
    {
      int r = tid & 31, kq = tid >> 5;     // kq 0..7
      float2 tA = *(const float2*)(Wsum + (size_t)(t0 + r)*KP + k0 + kq*2);
      At[kq*2+0][r] = tA.x;
      At[kq*2+1][r] = tA.y;
    }
#pragma unroll
    for (int it = 0; it < 2; ++it) {
      int q = tid + it*256;
      int kk = q >> 5, c4 = (q & 31) * 4;
      float4 tB = *(const float4*)(phi + (size_t)(k0 + kk)*NXO + xo0 + c4);
      int tcb = c4 >> 3, sub = c4 & 7;
      *(float4*)&Bp[tcb*132 + kk*8 + sub] = tB;
    }
    __syncthreads();
#pragma unroll
    for (int kk = 0; kk < 16; ++kk) {
      float a0 = At[kk][tr*2], a1 = At[kk][tr*2+1];
      float4 b0 = *(const float4*)&Bp[tc*132 + kk*8];
      float4 b1 = *(const float4*)&Bp[tc*132 + kk*8 + 4];
      float b[8] = {b0.x, b0.y, b0.z, b0.w, b1.x, b1.y, b1.z, b1.w};
#pragma unroll
      for (int c = 0; c < 8; ++c) {
        acc[0][c] = fmaf(a0, b[c], acc[0][c]);
        acc[1][c] = fmaf(a1, b[c], acc[1][c]);
      }
    }
    __syncthreads();
  }
#pragma unroll
  for (int r = 0; r < 2; ++r) {
    float4 o0 = {acc[r][0], acc[r][1], acc[r][2], acc[r][3]};
    float4 o1 = {acc[r][4], acc[r][5], acc[r][6], acc[r][7]};
    float* orow = out + (size_t)(t0 + tr*2 + r)*NXO + xo0 + tc*8;
    *(float4*)(orow)     = o0;
    *(float4*)(orow + 4) = o1;
  }
}

// ---------- launch ----------
extern "C" void kernel_launch(void* const* d_in, const int* in_sizes, int n_in,
                              void* d_out, int out_size, void* d_ws, size_t ws_size,
                              hipStream_t stream) {
  (void)in_sizes; (void)n_in; (void)out_size; (void)ws_size;
  const float* x_out = (const float*)d_in[0];
  const float* f     = (const float*)d_in[1];
  const float* xs    = (const float*)d_in[2];
  const float* vs    = (const float*)d_in[3];
  const float* W1    = (const float*)d_in[4];
  const float* b1    = (const float*)d_in[5];
  const float* W2    = (const float*)d_in[6];
  const float* b2    = (const float*)d_in[7];
  const float* W3    = (const float*)d_in[8];
  const float* b3    = (const float*)d_in[9];
  float* out = (float*)d_out;
  char* ws = (char*)d_ws;

  // Workspace map (22.3 MB):
  //   H2T   [0,          6,291,456)   48*65536*2 bf16 (rows 0..32 written)
  //   Gpart [6,291,456,  18,874,368)  64*1024*48*4
  //   Wsum  [18,874,368, 19,988,480)  1024*272*4
  //   W3e   [19,988,480, 20,040,704)  48*272*4
  //   phi   [20,040,704, 22,268,928)  272*2048*4
  unsigned short* H2T = (unsigned short*)(ws);
  float* Gpart = (float*)(ws + 6291456);
  float* Wsum  = (float*)(ws + 18874368);
  float* W3e   = (float*)(ws + 19988480);
  float* phi   = (float*)(ws + 20040704);

  hipLaunchKernelGGL(k0_prep,  dim3(48),   dim3(320), 0, stream, W3, b3, W3e);
  hipLaunchKernelGGL(k1_mlp,   dim3(256),  dim3(256), 0, stream, xs, vs, W1, b1, W2, b2, H2T);
  hipLaunchKernelGGL(k2c_phi,  dim3(2176), dim3(256), 0, stream, x_out, xs, phi);
  hipLaunchKernelGGL(k2_gemm,  dim3(1024), dim3(256), 0, stream, f, H2T, Gpart);
  hipLaunchKernelGGL(k2b_wsum, dim3(256),  dim3(256), 0, stream, Gpart, W3e, xs, vs, Wsum);
  hipLaunchKernelGGL(k3_out,   dim3(512),  dim3(256), 0, stream, Wsum, phi, out);
}

// Round 4
// 455.746 us; speedup vs baseline: 1.6302x; 1.0260x over previous
//
#include <hip/hip_runtime.h>
#include <hip/hip_bf16.h>

typedef short v8s __attribute__((ext_vector_type(8)));   // 8 x bf16 (4 VGPRs)
typedef float v4f __attribute__((ext_vector_type(4)));   // MFMA accumulator

#define NT    1024
#define NVX   65536
#define KTRUE 257
#define KP    272     // 257 padded to 17*16 (Wsum/phi leading dim)
#define NXO   2048
#define NJG   33      // Gsum cols: 32 H2 features + 1 rowsum (b3)
#define NKC   64      // split-K chunks (K-chunk = 1024)

// ---------- helpers ----------
static __device__ __forceinline__ unsigned short f2bf(float f) {
  unsigned int u = __float_as_uint(f);
  u += 0x7FFFu + ((u >> 16) & 1u);          // RNE
  return (unsigned short)(u >> 16);
}

// ---------- k1: MLP per (x,v) -> Bpk in MFMA-fragment order; also zero Gsum ----------
// Bpk element index: (kc*32+step)*1024 + jt*512 + lane*8 + e
//   where vx -> kc=vx>>10, step=(vx>>5)&31, g=(vx>>3)&3, e=vx&7, lane=g*16+(j&15), jt=j>>4.
__global__ __launch_bounds__(256) void k1_mlp(
    const float* __restrict__ xs, const float* __restrict__ vs,
    const float* __restrict__ W1, const float* __restrict__ b1,
    const float* __restrict__ W2, const float* __restrict__ b2,
    unsigned short* __restrict__ Bpk, float* __restrict__ Gsum) {
  int vx = blockIdx.x * 256 + threadIdx.x;
  if (vx < NT * NJG) Gsum[vx] = 0.f;        // zero-init for k2's atomics
  float x = xs[vx & 511];
  float v = vs[vx >> 9];
  float h2[32];
#pragma unroll
  for (int q = 0; q < 8; ++q) {
    float4 t = ((const float4*)b2)[q];
    h2[q*4+0] = t.x; h2[q*4+1] = t.y; h2[q*4+2] = t.z; h2[q*4+3] = t.w;
  }
#pragma unroll 4
  for (int i = 0; i < 64; ++i) {
    float h1 = fmaf(x, W1[i], fmaf(v, W1[64+i], b1[i]));
    h1 = fmaxf(h1, 0.f);
    const float4* w2r = (const float4*)(W2 + i*32);
#pragma unroll
    for (int q = 0; q < 8; ++q) {
      float4 t = w2r[q];
      h2[q*4+0] = fmaf(h1, t.x, h2[q*4+0]);
      h2[q*4+1] = fmaf(h1, t.y, h2[q*4+1]);
      h2[q*4+2] = fmaf(h1, t.z, h2[q*4+2]);
      h2[q*4+3] = fmaf(h1, t.w, h2[q*4+3]);
    }
  }
  // packed scatter store (32 x 2B; k1 is tiny, write-combining absorbs it)
  size_t base = ((size_t)(vx >> 10) * 32 + ((vx >> 5) & 31)) * 1024
              + (size_t)((vx >> 3) & 3) * 128 + (vx & 7);
#pragma unroll
  for (int j = 0; j < 32; ++j)
    Bpk[base + (size_t)(j >> 4) * 512 + (size_t)(j & 15) * 8] = f2bf(fmaxf(h2[j], 0.f));
}

// ---------- k2: streaming split-K bf16 MFMA GEMM, fully-coalesced loads ----------
// Gsum[t][j]   += sum_{vx in chunk kc} f[t][vx] * H2[vx][j]     (j = 0..31, via MFMA)
// Gsum[t][32]  += sum_{vx in chunk kc} f[t][vx]                 (rowsum, via VALU+shfl)
// grid = 64 kc * 16 mt; block 256 = 4 waves; wave w owns 16 rows.
__global__ __launch_bounds__(256) void k2_gemm(
    const float* __restrict__ f, const unsigned short* __restrict__ Bpk,
    float* __restrict__ Gsum) {
  const int tid  = threadIdx.x;
  const int kc   = blockIdx.x >> 4;     // 0..63
  const int mt   = blockIdx.x & 15;     // 0..15
  const int wave = tid >> 6;
  const int lane = tid & 63;
  const int frow = lane & 15;
  const int kg   = (lane >> 4) * 8;     // k offset within 32-wide step
  const int wrow0 = mt*64 + wave*16;
  const int row  = wrow0 + frow;
  const size_t kbase = (size_t)kc * 1024;

  const float* fp = f + (size_t)row * NVX + kbase + kg;
  const unsigned short* bq = Bpk + (size_t)kc * 32768 + (size_t)lane * 8;

  v4f acc0 = {0.f,0.f,0.f,0.f}, acc1 = {0.f,0.f,0.f,0.f};
  float rs = 0.f;

#pragma unroll 4
  for (int step = 0; step < 32; ++step) {
    const int o  = step * 32;        // f elements
    const int ob = step * 1024;      // Bpk elements
    float4 fa = *(const float4*)(fp + o);
    float4 fb = *(const float4*)(fp + o + 4);
    union { v8s v; __hip_bfloat162 h[4]; } au;
    au.h[0] = __float22bfloat162_rn(float2{fa.x, fa.y});
    au.h[1] = __float22bfloat162_rn(float2{fa.z, fa.w});
    au.h[2] = __float22bfloat162_rn(float2{fb.x, fb.y});
    au.h[3] = __float22bfloat162_rn(float2{fb.z, fb.w});
    rs += fa.x + fa.y + fa.z + fa.w + fb.x + fb.y + fb.z + fb.w;
    v8s b0 = *(const v8s*)(bq + ob);
    v8s b1 = *(const v8s*)(bq + ob + 512);
    acc0 = __builtin_amdgcn_mfma_f32_16x16x32_bf16(au.v, b0, acc0, 0, 0, 0);
    acc1 = __builtin_amdgcn_mfma_f32_16x16x32_bf16(au.v, b1, acc1, 0, 0, 0);
  }

  // rowsum reduce across the 4 lanes sharing frow (lanes frow, +16, +32, +48)
  rs += __shfl_xor(rs, 16);
  rs += __shfl_xor(rs, 32);

  // C/D layout: col = lane&15 (=j), row = (lane>>4)*4 + reg  [m89-verified]
  const int r4 = (lane >> 4) * 4;
#pragma unroll
  for (int r = 0; r < 4; ++r) {
    atomicAdd(&Gsum[(size_t)(wrow0 + r4 + r)*NJG + frow],      acc0[r]);
    atomicAdd(&Gsum[(size_t)(wrow0 + r4 + r)*NJG + 16 + frow], acc1[r]);
  }
  if (lane < 16) atomicAdd(&Gsum[(size_t)row*NJG + 32], rs);
}

// ---------- k2b: Wsum[t][k] = scale * ( sum_{j<32} Gsum[t][j]*W3[j][k] + Gsum[t][32]*b3[k] )
// grid 256 blocks * 256 thr; wave w handles row t = blk*4 + w.
__global__ __launch_bounds__(256) void k2b_wsum(
    const float* __restrict__ Gsum, const float* __restrict__ W3,
    const float* __restrict__ b3, const float* __restrict__ xs,
    const float* __restrict__ vs, float* __restrict__ Wsum) {
  __shared__ float gs[4][NJG];
  const int tid = threadIdx.x, wave = tid >> 6, lane = tid & 63;
  const int t = blockIdx.x * 4 + wave;
  const float scale = (xs[1] - xs[0]) * (vs[1] - vs[0]);   // hx*hv
  if (lane < NJG) gs[wave][lane] = Gsum[(size_t)t*NJG + lane];
  __syncthreads();
#pragma unroll
  for (int i = 0; i < 5; ++i) {
    int k = lane + i*64;
    if (k < KP) {
      float val = 0.f;
      if (k < KTRUE) {
        float acc = gs[wave][32] * b3[k];
#pragma unroll
        for (int j = 0; j < 32; ++j) acc = fmaf(gs[wave][j], W3[j*KTRUE + k], acc);
        val = acc * scale;
      }
      Wsum[(size_t)t*KP + k] = val;
    }
  }
}

// ---------- k2c: phi[272][2048]; one sincos per (freq,xo); rows >=257 zero ----------
__global__ __launch_bounds__(256) void k2c_phi(const float* __restrict__ x_out,
                                               const float* __restrict__ xs,
                                               float* __restrict__ phi) {
  int idx = blockIdx.x * 256 + threadIdx.x;       // < 129*2048
  int fq = idx >> 11, xo = idx & 2047;
  float wmul = 6.283185307179586f / (xs[511] - xs[0]);
  float x = x_out[xo];
  float s, c;
  __sincosf((float)fq * wmul * x, &s, &c);
  phi[(size_t)(128 + fq)*NXO + xo] = c;           // cos rows 128..256
  if (fq >= 1) phi[(size_t)(fq - 1)*NXO + xo] = s; // sin rows 0..127
  if (idx < 15*NXO) phi[(size_t)KTRUE*NXO + idx] = 0.f;  // zero pad rows 257..271
}

// ---------- k3: out[1024][2048] = Wsum[1024][272] @ phi[272][2048]  (fp32 tiled)
__global__ __launch_bounds__(256) void k3_out(
    const float* __restrict__ Wsum, const float* __restrict__ phi,
    float* __restrict__ out) {
  __shared__ float At[16][32];     // [kk][row]
  __shared__ float Bp[16*132];     // [tc][kk*8+sub], 132-pad per tc
  const int tid = threadIdx.x;
  const int bt = blockIdx.x >> 4;   // 0..31
  const int bx = blockIdx.x & 15;   // 0..15
  const int t0 = bt*32, xo0 = bx*128;
  const int tr = tid >> 4, tc = tid & 15;   // rows tr*2..+2, cols tc*8..+8
  float acc[2][8];
#pragma unroll
  for (int r = 0; r < 2; ++r)
#pragma unroll
    for (int c = 0; c < 8; ++c) acc[r][c] = 0.f;

  for (int ks = 0; ks < 17; ++ks) {
    int k0 = ks * 16;
    {
      int r = tid & 31, kq = tid >> 5;     // kq 0..7
      float2 tA = *(const float2*)(Wsum + (size_t)(t0 + r)*KP + k0 + kq*2);
      At[kq*2+0][r] = tA.x;
      At[kq*2+1][r] = tA.y;
    }
#pragma unroll
    for (int it = 0; it < 2; ++it) {
      int q = tid + it*256;
      int kk = q >> 5, c4 = (q & 31) * 4;
      float4 tB = *(const float4*)(phi + (size_t)(k0 + kk)*NXO + xo0 + c4);
      int tcb = c4 >> 3, sub = c4 & 7;
      *(float4*)&Bp[tcb*132 + kk*8 + sub] = tB;
    }
    __syncthreads();
#pragma unroll
    for (int kk = 0; kk < 16; ++kk) {
      float a0 = At[kk][tr*2], a1 = At[kk][tr*2+1];
      float4 b0 = *(const float4*)&Bp[tc*132 + kk*8];
      float4 b1 = *(const float4*)&Bp[tc*132 + kk*8 + 4];
      float b[8] = {b0.x, b0.y, b0.z, b0.w, b1.x, b1.y, b1.z, b1.w};
#pragma unroll
      for (int c = 0; c < 8; ++c) {
        acc[0][c] = fmaf(a0, b[c], acc[0][c]);
        acc[1][c] = fmaf(a1, b[c], acc[1][c]);
      }
    }
    __syncthreads();
  }
#pragma unroll
  for (int r = 0; r < 2; ++r) {
    float4 o0 = {acc[r][0], acc[r][1], acc[r][2], acc[r][3]};
    float4 o1 = {acc[r][4], acc[r][5], acc[r][6], acc[r][7]};
    float* orow = out + (size_t)(t0 + tr*2 + r)*NXO + xo0 + tc*8;
    *(float4*)(orow)     = o0;
    *(float4*)(orow + 4) = o1;
  }
}

// ---------- launch ----------
extern "C" void kernel_launch(void* const* d_in, const int* in_sizes, int n_in,
                              void* d_out, int out_size, void* d_ws, size_t ws_size,
                              hipStream_t stream) {
  (void)in_sizes; (void)n_in; (void)out_size; (void)ws_size;
  const float* x_out = (const float*)d_in[0];
  const float* f     = (const float*)d_in[1];
  const float* xs    = (const float*)d_in[2];
  const float* vs    = (const float*)d_in[3];
  const float* W1    = (const float*)d_in[4];
  const float* b1    = (const float*)d_in[5];
  const float* W2    = (const float*)d_in[6];
  const float* b2    = (const float*)d_in[7];
  const float* W3    = (const float*)d_in[8];
  const float* b3    = (const float*)d_in[9];
  float* out = (float*)d_out;
  char* ws = (char*)d_ws;

  // Workspace map (7.7 MB):
  //   Bpk  [0,         4,194,304)   64*32*1024 * 2B bf16, fragment-ordered
  //   Gsum [4,194,304, 4,329,472)   1024*33*4
  //   Wsum [4,329,472, 5,443,584)   1024*272*4
  //   phi  [5,443,584, 7,671,808)   272*2048*4
  unsigned short* Bpk = (unsigned short*)(ws);
  float* Gsum  = (float*)(ws + 4194304);
  float* Wsum  = (float*)(ws + 4329472);
  float* phi   = (float*)(ws + 5443584);

  hipLaunchKernelGGL(k1_mlp,   dim3(256),  dim3(256), 0, stream, xs, vs, W1, b1, W2, b2, Bpk, Gsum);
  hipLaunchKernelGGL(k2c_phi,  dim3(1032), dim3(256), 0, stream, x_out, xs, phi);
  hipLaunchKernelGGL(k2_gemm,  dim3(1024), dim3(256), 0, stream, f, Bpk, Gsum);
  hipLaunchKernelGGL(k2b_wsum, dim3(256),  dim3(256), 0, stream, Gsum, W3, b3, xs, vs, Wsum);
  hipLaunchKernelGGL(k3_out,   dim3(512),  dim3(256), 0, stream, Wsum, phi, out);
}